// Round 2
// baseline (201.994 us; speedup 1.0000x reference)
//
#include <hip/hip_runtime.h>
#include <hip/hip_bf16.h>
#include <stdint.h>

#define HEADS 12
#define HD 64
#define SEQ 1024
#define CDIM 768

typedef __attribute__((ext_vector_type(8))) short bfrag;   // 8 bf16 (4 VGPRs)
typedef __attribute__((ext_vector_type(4))) float facc;    // 4 fp32 accum

__device__ __forceinline__ ushort f2bf(float f) {
    union { float f; uint32_t u; } v; v.f = f;
    uint32_t u = v.u;
    uint32_t r = (u + 0x7FFFu + ((u >> 16) & 1u)) >> 16;
    return (ushort)r;
}

// ---------------- fp32 -> bf16 convert ----------------
__global__ void cvt_f32_bf16(const float* __restrict__ s, ushort* __restrict__ d, int n) {
    int i = (blockIdx.x * 256 + threadIdx.x) * 4;
    if (i + 3 < n) {
        float4 v = *(const float4*)(s + i);
        ushort4 o;
        o.x = f2bf(v.x); o.y = f2bf(v.y); o.z = f2bf(v.z); o.w = f2bf(v.w);
        *(ushort4*)(d + i) = o;
    }
}

// ---------------- NT GEMM, 128x128 tile, BK=32, bf16 MFMA ----------------
// A: [M][768] bf16 row-major, B: [N][768] bf16 row-major, C[m][o] = sum_k A[m][k]*B[o][k]
// EPI 0: scatter to q/k/v buffers [b][h][n][64] bf16, q scaled by 0.125
// EPI 1: out fp32 [M][768] += proj bias
template<int EPI>
__global__ __launch_bounds__(256) void gemm_nt(
    const ushort* __restrict__ A, const ushort* __restrict__ Bm,
    ushort* __restrict__ qb, ushort* __restrict__ kb, ushort* __restrict__ vb,
    const float* __restrict__ projb, float* __restrict__ out)
{
    __shared__ ushort As[128 * 32];
    __shared__ ushort Bs[128 * 32];
    const int t = threadIdx.x;
    const int w = t >> 6, l = t & 63;
    const int wm = w >> 1, wn = w & 1;
    const int lr = l & 15, lg = l >> 4;
    const int m0 = blockIdx.x * 128;
    const int o0 = blockIdx.y * 128;

    facc acc[4][4] = {};

    const int arow = t >> 1, acolh = (t & 1) << 4;  // staging: row 0..127, col half 0/16
    const ushort* Ag = A + (size_t)(m0 + arow) * CDIM + acolh;
    const ushort* Bg = Bm + (size_t)(o0 + arow) * CDIM + acolh;
    ushort* AsW = &As[arow * 32 + acolh];
    ushort* BsW = &Bs[arow * 32 + acolh];

    for (int k0 = 0; k0 < CDIM; k0 += 32) {
        bfrag a0 = *(const bfrag*)(Ag + k0);
        bfrag a1 = *(const bfrag*)(Ag + k0 + 8);
        bfrag b0 = *(const bfrag*)(Bg + k0);
        bfrag b1 = *(const bfrag*)(Bg + k0 + 8);
        __syncthreads();
        *(bfrag*)(AsW) = a0; *(bfrag*)(AsW + 8) = a1;
        *(bfrag*)(BsW) = b0; *(bfrag*)(BsW + 8) = b1;
        __syncthreads();
        bfrag af[4], bf[4];
#pragma unroll
        for (int m = 0; m < 4; ++m)
            af[m] = *(const bfrag*)&As[(wm * 64 + m * 16 + lr) * 32 + lg * 8];
#pragma unroll
        for (int n = 0; n < 4; ++n)
            bf[n] = *(const bfrag*)&Bs[(wn * 64 + n * 16 + lr) * 32 + lg * 8];
#pragma unroll
        for (int m = 0; m < 4; ++m)
#pragma unroll
            for (int n = 0; n < 4; ++n)
                acc[m][n] = __builtin_amdgcn_mfma_f32_16x16x32_bf16(af[m], bf[n], acc[m][n], 0, 0, 0);
    }

    if (EPI == 0) {
        // o = o0 + wn*64 + n*16 + lr ; o -> (s, h, d): s = o/768, h = (o%768)/64, d = o%64
        const int tsel = o0 / CDIM;               // uniform per block
        const int h_base = (o0 % CDIM) / 64;
        ushort* dst = (tsel == 0) ? qb : ((tsel == 1) ? kb : vb);
        const float scl = (tsel == 0) ? 0.125f : 1.0f;
#pragma unroll
        for (int m = 0; m < 4; ++m) {
            int grow = m0 + wm * 64 + m * 16 + lg * 4;
#pragma unroll
            for (int n = 0; n < 4; ++n) {
                int h = h_base + wn;
                int d = n * 16 + lr;
#pragma unroll
                for (int r = 0; r < 4; ++r) {
                    int row = grow + r;
                    int b = row >> 10, nn = row & 1023;
                    dst[(((size_t)(b * HEADS + h)) * SEQ + nn) * HD + d] = f2bf(acc[m][n][r] * scl);
                }
            }
        }
    } else {
#pragma unroll
        for (int m = 0; m < 4; ++m) {
            int grow = m0 + wm * 64 + m * 16 + lg * 4;
#pragma unroll
            for (int n = 0; n < 4; ++n) {
                int o = o0 + wn * 64 + n * 16 + lr;
                float bias = projb[o];
#pragma unroll
                for (int r = 0; r < 4; ++r)
                    out[(size_t)(grow + r) * CDIM + o] = acc[m][n][r] + bias;
            }
        }
    }
}

// ---------------- fused flash attention with rel-pos bias ----------------
// grid: (16 q-tiles, 96 bh). 256 threads = 4 waves, wave w owns q rows [q0+16w, q0+16w+16)
__global__ __launch_bounds__(256) void attn_kernel(
    const ushort* __restrict__ qbuf, const ushort* __restrict__ kbuf,
    const ushort* __restrict__ vbuf, const float* __restrict__ biasf,
    ushort* __restrict__ attn_out)
{
    __shared__ ushort Ks[64 * 72];       // K chunk [kv][hd], padded
    __shared__ ushort Vt[64 * 72];       // V chunk transposed [hd][kv], padded
    __shared__ ushort Ps[4][16 * 72];    // per-wave P tile [q][kv], padded

    const int t = threadIdx.x;
    const int w = t >> 6, l = t & 63;
    const int lr = l & 15, lg = l >> 4;
    const int q0 = blockIdx.x * 64;
    const int bh = blockIdx.y;           // b*12 + h
    const int h = bh % HEADS;
    const int b = bh / HEADS;
    const size_t headoff = (size_t)bh * SEQ * HD;

    // Q fragments (q pre-scaled by 0.125 at QKV epilogue)
    const ushort* Qp = qbuf + headoff + (size_t)(q0 + w * 16 + lr) * HD;
    bfrag aQ0 = *(const bfrag*)(Qp + lg * 8);
    bfrag aQ1 = *(const bfrag*)(Qp + 32 + lg * 8);

    float mrun[4], lrun[4];
    facc Ov[4] = {};
#pragma unroll
    for (int r = 0; r < 4; ++r) { mrun[r] = -1e30f; lrun[r] = 0.0f; }

    // fp32 bias, row (h, q0 + w*16 + ...)
    const float* bp = biasf + ((size_t)h * SEQ + (q0 + w * 16)) * SEQ;

    for (int kv0 = 0; kv0 < SEQ; kv0 += 64) {
        __syncthreads();
        if (t < 128) {
            // stage K: 64 rows x 64 cols, 2 threads/row, 32 cols each
            int row = t >> 1, colh = (t & 1) * 32;
            const ushort* kg = kbuf + headoff + (size_t)(kv0 + row) * HD + colh;
            ushort* kl = &Ks[row * 72 + colh];
#pragma unroll
            for (int i = 0; i < 4; ++i)
                *(bfrag*)(kl + 8 * i) = *(const bfrag*)(kg + 8 * i);
        } else {
            // stage V transposed: thread handles 4 kv rows x 8 d cols (full 64x64 tile)
            int tt = t - 128;
            int p = tt >> 3, g = tt & 7;      // p: kv quad 0..15, g: d group 0..7
            const ushort* vg = vbuf + headoff + (size_t)(kv0 + 4 * p) * HD + g * 8;
            bfrag v0 = *(const bfrag*)(vg);
            bfrag v1 = *(const bfrag*)(vg + HD);
            bfrag v2 = *(const bfrag*)(vg + 2 * HD);
            bfrag v3 = *(const bfrag*)(vg + 3 * HD);
#pragma unroll
            for (int i = 0; i < 8; ++i) {
                uint32_t pk0 = (uint32_t)(uint16_t)v0[i] | ((uint32_t)(uint16_t)v1[i] << 16);
                uint32_t pk1 = (uint32_t)(uint16_t)v2[i] | ((uint32_t)(uint16_t)v3[i] << 16);
                *(uint32_t*)&Vt[(g * 8 + i) * 72 + 4 * p] = pk0;
                *(uint32_t*)&Vt[(g * 8 + i) * 72 + 4 * p + 2] = pk1;
            }
        }
        __syncthreads();

        // S = Q K^T (+ bias); C layout: col kv = c*16+lr, row q = lg*4+r
        facc S[4];
#pragma unroll
        for (int c = 0; c < 4; ++c) {
            bfrag k0f = *(const bfrag*)&Ks[(c * 16 + lr) * 72 + lg * 8];
            bfrag k1f = *(const bfrag*)&Ks[(c * 16 + lr) * 72 + 32 + lg * 8];
            facc s = {};
            s = __builtin_amdgcn_mfma_f32_16x16x32_bf16(aQ0, k0f, s, 0, 0, 0);
            s = __builtin_amdgcn_mfma_f32_16x16x32_bf16(aQ1, k1f, s, 0, 0, 0);
            S[c] = s;
        }
#pragma unroll
        for (int c = 0; c < 4; ++c)
#pragma unroll
            for (int r = 0; r < 4; ++r)
                S[c][r] += bp[(size_t)(lg * 4 + r) * SEQ + kv0 + c * 16 + lr];

        // online softmax (16-lane groups hold one q row)
        float mnew[4], alpha[4];
#pragma unroll
        for (int r = 0; r < 4; ++r) {
            float mx = fmaxf(fmaxf(S[0][r], S[1][r]), fmaxf(S[2][r], S[3][r]));
            mx = fmaxf(mx, __shfl_xor(mx, 1));
            mx = fmaxf(mx, __shfl_xor(mx, 2));
            mx = fmaxf(mx, __shfl_xor(mx, 4));
            mx = fmaxf(mx, __shfl_xor(mx, 8));
            mnew[r] = fmaxf(mrun[r], mx);
            alpha[r] = __expf(mrun[r] - mnew[r]);
            mrun[r] = mnew[r];
        }
#pragma unroll
        for (int c = 0; c < 4; ++c)
#pragma unroll
            for (int r = 0; r < 4; ++r) {
                float p = __expf(S[c][r] - mnew[r]);
                S[c][r] = p;
                Ps[w][(lg * 4 + r) * 72 + c * 16 + lr] = f2bf(p);
            }
#pragma unroll
        for (int r = 0; r < 4; ++r) {
            float s = S[0][r] + S[1][r] + S[2][r] + S[3][r];
            s += __shfl_xor(s, 1);
            s += __shfl_xor(s, 2);
            s += __shfl_xor(s, 4);
            s += __shfl_xor(s, 8);
            lrun[r] = lrun[r] * alpha[r] + s;
        }
#pragma unroll
        for (int d = 0; d < 4; ++d)
#pragma unroll
            for (int r = 0; r < 4; ++r)
                Ov[d][r] *= alpha[r];

        // PV: O[q][dd] += P[q][kv] * V[kv][dd]
        bfrag aP0 = *(const bfrag*)&Ps[w][lr * 72 + lg * 8];
        bfrag aP1 = *(const bfrag*)&Ps[w][lr * 72 + 32 + lg * 8];
#pragma unroll
        for (int d = 0; d < 4; ++d) {
            bfrag bv0 = *(const bfrag*)&Vt[(d * 16 + lr) * 72 + lg * 8];
            bfrag bv1 = *(const bfrag*)&Vt[(d * 16 + lr) * 72 + 32 + lg * 8];
            Ov[d] = __builtin_amdgcn_mfma_f32_16x16x32_bf16(aP0, bv0, Ov[d], 0, 0, 0);
            Ov[d] = __builtin_amdgcn_mfma_f32_16x16x32_bf16(aP1, bv1, Ov[d], 0, 0, 0);
        }
    }

    // epilogue: normalize, write [b][n][h*64+d] bf16
    ushort* op = attn_out + ((size_t)b * SEQ + q0 + w * 16) * CDIM + h * HD;
#pragma unroll
    for (int r = 0; r < 4; ++r) {
        float rl = 1.0f / lrun[r];
#pragma unroll
        for (int d = 0; d < 4; ++d)
            op[(size_t)(lg * 4 + r) * CDIM + d * 16 + lr] = f2bf(Ov[d][r] * rl);
    }
}

// ---------------- launch ----------------
extern "C" void kernel_launch(void* const* d_in, const int* in_sizes, int n_in,
                              void* d_out, int out_size, void* d_ws, size_t ws_size,
                              hipStream_t stream) {
    const float* x     = (const float*)d_in[0];   // (8,1024,768)
    const float* rel   = (const float*)d_in[1];   // (12,1024,1024)
    const float* qkvw  = (const float*)d_in[2];   // (2304,768)
    const float* projw = (const float*)d_in[3];   // (768,768)
    const float* projb = (const float*)d_in[4];   // (768,)
    float* out = (float*)d_out;

    char* ws = (char*)d_ws;
    ushort* xbf   = (ushort*)(ws);                 // 8192*768         = 6,291,456 elems
    ushort* wbf   = (ushort*)(ws + 12582912);      // 2304*768         = 1,769,472
    ushort* pwbf  = (ushort*)(ws + 16121856);      // 768*768          =   589,824
    ushort* qb    = (ushort*)(ws + 17301504);      // 8*12*1024*64     = 6,291,456
    ushort* kb    = (ushort*)(ws + 29884416);
    ushort* vb    = (ushort*)(ws + 42467328);
    ushort* attnb = (ushort*)(ws + 55050240);      // ends at 67,633,152 bytes

    cvt_f32_bf16<<<6144, 256, 0, stream>>>(x, xbf, 6291456);
    cvt_f32_bf16<<<1728, 256, 0, stream>>>(qkvw, wbf, 1769472);
    cvt_f32_bf16<<<576, 256, 0, stream>>>(projw, pwbf, 589824);

    gemm_nt<0><<<dim3(64, 18), 256, 0, stream>>>(xbf, wbf, qb, kb, vb, nullptr, nullptr);
    attn_kernel<<<dim3(16, 96), 256, 0, stream>>>(qb, kb, vb, rel, attnb);
    gemm_nt<1><<<dim3(64, 6), 256, 0, stream>>>(attnb, pwbf, nullptr, nullptr, nullptr, projb, out);
}

// Round 3
// 177.146 us; speedup vs baseline: 1.1403x; 1.1403x over previous
//
#include <hip/hip_runtime.h>
#include <hip/hip_bf16.h>
#include <stdint.h>

#define HEADS 12
#define HD 64
#define SEQ 1024
#define CDIM 768

typedef __attribute__((ext_vector_type(8))) short bfrag;   // 8 bf16 (4 VGPRs)
typedef __attribute__((ext_vector_type(4))) float facc;    // 4 fp32 accum

__device__ __forceinline__ ushort f2bf(float f) {
    union { float f; uint32_t u; } v; v.f = f;
    uint32_t u = v.u;
    uint32_t r = (u + 0x7FFFu + ((u >> 16) & 1u)) >> 16;
    return (ushort)r;
}

// ---------------- fp32 -> bf16 convert ----------------
__global__ void cvt_f32_bf16(const float* __restrict__ s, ushort* __restrict__ d, int n) {
    int i = (blockIdx.x * 256 + threadIdx.x) * 4;
    if (i + 3 < n) {
        float4 v = *(const float4*)(s + i);
        ushort4 o;
        o.x = f2bf(v.x); o.y = f2bf(v.y); o.z = f2bf(v.z); o.w = f2bf(v.w);
        *(ushort4*)(d + i) = o;
    }
}

#define GLOAD16(gsrc, ldst) \
    __builtin_amdgcn_global_load_lds((const __attribute__((address_space(1))) uint32_t*)(gsrc), \
                                     (__attribute__((address_space(3))) uint32_t*)(ldst), 16, 0, 0)

// ---------------- NT GEMM, 128x128 tile, BK=32, global_load_lds staging ----------------
// A: [M][768] bf16 row-major, B: [N][768] bf16 row-major, C[m][o] = sum_k A[m][k]*B[o][k]
template<int EPI>
__global__ __launch_bounds__(256) void gemm_nt(
    const ushort* __restrict__ A, const ushort* __restrict__ Bm,
    ushort* __restrict__ qb, ushort* __restrict__ kb, ushort* __restrict__ vb,
    const float* __restrict__ projb, float* __restrict__ out)
{
    __shared__ ushort As[128 * 32];
    __shared__ ushort Bs[128 * 32];
    const int t = threadIdx.x;
    const int w = t >> 6, l = t & 63;
    const int wm = w >> 1, wn = w & 1;
    const int lr = l & 15, lg = l >> 4;
    const int m0 = blockIdx.x * 128;
    const int o0 = blockIdx.y * 128;

    facc acc[4][4] = {};

    // staging: batch j in {0,1}: LDS ushort offset = j*2048 + w*512 + lane*8
    // -> row = j*64 + w*16 + (lane>>2), col = (lane&3)*8  (tile [128][32] linear)
    const int srow = w * 16 + (l >> 2);
    const int scol = (l & 3) * 8;
    const ushort* Ag = A + (size_t)(m0 + srow) * CDIM + scol;
    const ushort* Bg = Bm + (size_t)(o0 + srow) * CDIM + scol;

    for (int k0 = 0; k0 < CDIM; k0 += 32) {
        __syncthreads();
        GLOAD16(Ag + k0,             As + w * 512);
        GLOAD16(Ag + 64 * CDIM + k0, As + 2048 + w * 512);
        GLOAD16(Bg + k0,             Bs + w * 512);
        GLOAD16(Bg + 64 * CDIM + k0, Bs + 2048 + w * 512);
        __syncthreads();
        bfrag af[4], bf[4];
#pragma unroll
        for (int m = 0; m < 4; ++m)
            af[m] = *(const bfrag*)&As[(wm * 64 + m * 16 + lr) * 32 + lg * 8];
#pragma unroll
        for (int n = 0; n < 4; ++n)
            bf[n] = *(const bfrag*)&Bs[(wn * 64 + n * 16 + lr) * 32 + lg * 8];
#pragma unroll
        for (int m = 0; m < 4; ++m)
#pragma unroll
            for (int n = 0; n < 4; ++n)
                acc[m][n] = __builtin_amdgcn_mfma_f32_16x16x32_bf16(af[m], bf[n], acc[m][n], 0, 0, 0);
    }

    if (EPI == 0) {
        const int tsel = o0 / CDIM;
        const int h_base = (o0 % CDIM) / 64;
        ushort* dst = (tsel == 0) ? qb : ((tsel == 1) ? kb : vb);
        const float scl = (tsel == 0) ? 0.125f : 1.0f;
#pragma unroll
        for (int m = 0; m < 4; ++m) {
            int grow = m0 + wm * 64 + m * 16 + lg * 4;
#pragma unroll
            for (int n = 0; n < 4; ++n) {
                int h = h_base + wn;
                int d = n * 16 + lr;
#pragma unroll
                for (int r = 0; r < 4; ++r) {
                    int row = grow + r;
                    int b = row >> 10, nn = row & 1023;
                    dst[(((size_t)(b * HEADS + h)) * SEQ + nn) * HD + d] = f2bf(acc[m][n][r] * scl);
                }
            }
        }
    } else {
#pragma unroll
        for (int m = 0; m < 4; ++m) {
            int grow = m0 + wm * 64 + m * 16 + lg * 4;
#pragma unroll
            for (int n = 0; n < 4; ++n) {
                int o = o0 + wn * 64 + n * 16 + lr;
                float bias = projb[o];
#pragma unroll
                for (int r = 0; r < 4; ++r)
                    out[(size_t)(grow + r) * CDIM + o] = acc[m][n][r] + bias;
            }
        }
    }
}

// ---------------- fused flash attention, swapped-QK^T (S^T) form ----------------
// grid: 768 blocks (swizzled). Block = 128 q rows; 4 waves x 32 q rows (2 subtiles of 16).
// S^T: per c-tile, lane holds S[q = lane&15][kv = c*16 + (lane>>4)*4 + r].
__global__ __launch_bounds__(256) void attn_kernel(
    const ushort* __restrict__ qbuf, const ushort* __restrict__ kbuf,
    const ushort* __restrict__ vbuf, const float* __restrict__ biasf,
    ushort* __restrict__ attn_out)
{
    __shared__ ushort Ks[64 * 72];       // K chunk [kv][hd], padded
    __shared__ ushort Vt[64 * 72];       // V chunk transposed [hd][kv], padded
    __shared__ ushort Ps[4][32 * 72];    // per-wave P [q=32][kv=64], padded

    const int t = threadIdx.x;
    const int w = t >> 6, l = t & 63;
    const int lr = l & 15, lg = l >> 4;

    // XCD-chunked swizzle: lid = h*64 + qt*8 + b; XCD x gets 96 consecutive lids (h-contiguous)
    const int bid = blockIdx.x;
    const int lid = (bid & 7) * 96 + (bid >> 3);
    const int h  = lid >> 6;
    const int qt = (lid >> 3) & 7;
    const int b  = lid & 7;

    const int q0 = qt * 128;
    const size_t headoff = (size_t)(b * HEADS + h) * SEQ * HD;
    const int qrb = q0 + w * 32;

    // Q fragments (q pre-scaled by 0.125): aQ[n][ks]
    bfrag aQ[2][2];
#pragma unroll
    for (int n = 0; n < 2; ++n) {
        const ushort* Qp = qbuf + headoff + (size_t)(qrb + n * 16 + lr) * HD;
        aQ[n][0] = *(const bfrag*)(Qp + lg * 8);
        aQ[n][1] = *(const bfrag*)(Qp + 32 + lg * 8);
    }

    float mrun[2] = {-1e30f, -1e30f}, lrun[2] = {0.0f, 0.0f};
    facc Ov[2][4] = {};

    const float* bprow[2];
#pragma unroll
    for (int n = 0; n < 2; ++n)
        bprow[n] = biasf + ((size_t)h * SEQ + qrb + n * 16 + lr) * SEQ;

    // staging indices
    const int krow = t >> 3, kc = (t & 7) * 8;          // K: 2 chunks/thread
    const int p2 = t & 31, vg_ = t >> 5;                // V: kv-pair fast (2-way free banks)

    for (int kv0 = 0; kv0 < SEQ; kv0 += 64) {
        __syncthreads();
        {
            const ushort* kg = kbuf + headoff + (size_t)(kv0 + krow) * HD + kc;
            *(bfrag*)&Ks[krow * 72 + kc] = *(const bfrag*)kg;
            *(bfrag*)&Ks[(krow + 32) * 72 + kc] = *(const bfrag*)(kg + (size_t)32 * HD);
        }
        {
            const ushort* vg = vbuf + headoff + (size_t)(kv0 + 2 * p2) * HD + vg_ * 8;
            bfrag v0 = *(const bfrag*)vg;
            bfrag v1 = *(const bfrag*)(vg + HD);
#pragma unroll
            for (int i = 0; i < 8; ++i) {
                uint32_t pk = (uint32_t)(uint16_t)v0[i] | ((uint32_t)(uint16_t)v1[i] << 16);
                *(uint32_t*)&Vt[(vg_ * 8 + i) * 72 + 2 * p2] = pk;
            }
        }
        __syncthreads();

        // S^T = K Q^T : St[n][c], kv = c*16 + lg*4 + r, q = lr
        facc St[2][4];
#pragma unroll
        for (int c = 0; c < 4; ++c) {
            bfrag kf0 = *(const bfrag*)&Ks[(c * 16 + lr) * 72 + lg * 8];
            bfrag kf1 = *(const bfrag*)&Ks[(c * 16 + lr) * 72 + 32 + lg * 8];
#pragma unroll
            for (int n = 0; n < 2; ++n) {
                facc s = {};
                s = __builtin_amdgcn_mfma_f32_16x16x32_bf16(kf0, aQ[n][0], s, 0, 0, 0);
                s = __builtin_amdgcn_mfma_f32_16x16x32_bf16(kf1, aQ[n][1], s, 0, 0, 0);
                St[n][c] = s;
            }
        }
        // bias add: float4 (kv contiguous in regs)
#pragma unroll
        for (int n = 0; n < 2; ++n)
#pragma unroll
            for (int c = 0; c < 4; ++c) {
                float4 bv = *(const float4*)(bprow[n] + kv0 + c * 16 + lg * 4);
                St[n][c][0] += bv.x; St[n][c][1] += bv.y;
                St[n][c][2] += bv.z; St[n][c][3] += bv.w;
            }

        // online softmax: each lane owns row q=lr (subtile n); reduce across lg via 2 shfl
        float al[2];
#pragma unroll
        for (int n = 0; n < 2; ++n) {
            float mx = St[n][0][0];
#pragma unroll
            for (int c = 0; c < 4; ++c)
#pragma unroll
                for (int r = 0; r < 4; ++r) mx = fmaxf(mx, St[n][c][r]);
            mx = fmaxf(mx, __shfl_xor(mx, 16));
            mx = fmaxf(mx, __shfl_xor(mx, 32));
            float mnew = fmaxf(mrun[n], mx);
            al[n] = __expf(mrun[n] - mnew);
            mrun[n] = mnew;
            float sum = 0.0f;
#pragma unroll
            for (int c = 0; c < 4; ++c) {
#pragma unroll
                for (int r = 0; r < 4; ++r) {
                    float p = __expf(St[n][c][r] - mnew);
                    St[n][c][r] = p;
                    sum += p;
                }
                ushort4 pk = {f2bf(St[n][c][0]), f2bf(St[n][c][1]),
                              f2bf(St[n][c][2]), f2bf(St[n][c][3])};
                *(ushort4*)&Ps[w][(n * 16 + lr) * 72 + c * 16 + lg * 4] = pk;
            }
            sum += __shfl_xor(sum, 16);
            sum += __shfl_xor(sum, 32);
            lrun[n] = lrun[n] * al[n] + sum;
        }

        // rescale O by alpha (cross-lane: row q=lg*4+r lives in lane lg*4+r)
#pragma unroll
        for (int n = 0; n < 2; ++n) {
#pragma unroll
            for (int r = 0; r < 4; ++r) {
                float a = __shfl(al[n], lg * 4 + r);
#pragma unroll
                for (int d = 0; d < 4; ++d) Ov[n][d][r] *= a;
            }
        }

        // PV: A-fragments from Ps (wave-private, wave-synchronous)
        bfrag aP[2][2];
#pragma unroll
        for (int n = 0; n < 2; ++n) {
            aP[n][0] = *(const bfrag*)&Ps[w][(n * 16 + lr) * 72 + lg * 8];
            aP[n][1] = *(const bfrag*)&Ps[w][(n * 16 + lr) * 72 + 32 + lg * 8];
        }
#pragma unroll
        for (int d = 0; d < 4; ++d) {
            bfrag bv0 = *(const bfrag*)&Vt[(d * 16 + lr) * 72 + lg * 8];
            bfrag bv1 = *(const bfrag*)&Vt[(d * 16 + lr) * 72 + 32 + lg * 8];
#pragma unroll
            for (int n = 0; n < 2; ++n) {
                Ov[n][d] = __builtin_amdgcn_mfma_f32_16x16x32_bf16(aP[n][0], bv0, Ov[n][d], 0, 0, 0);
                Ov[n][d] = __builtin_amdgcn_mfma_f32_16x16x32_bf16(aP[n][1], bv1, Ov[n][d], 0, 0, 0);
            }
        }
    }

    // epilogue: normalize, write [b][n][h*64+d] bf16
#pragma unroll
    for (int n = 0; n < 2; ++n) {
        ushort* op = attn_out + ((size_t)b * SEQ + qrb + n * 16) * CDIM + h * HD;
#pragma unroll
        for (int r = 0; r < 4; ++r) {
            float ll = __shfl(lrun[n], lg * 4 + r);
            float rl = 1.0f / ll;
#pragma unroll
            for (int d = 0; d < 4; ++d)
                op[(size_t)(lg * 4 + r) * CDIM + d * 16 + lr] = f2bf(Ov[n][d][r] * rl);
        }
    }
}

// ---------------- launch ----------------
extern "C" void kernel_launch(void* const* d_in, const int* in_sizes, int n_in,
                              void* d_out, int out_size, void* d_ws, size_t ws_size,
                              hipStream_t stream) {
    const float* x     = (const float*)d_in[0];   // (8,1024,768)
    const float* rel   = (const float*)d_in[1];   // (12,1024,1024)
    const float* qkvw  = (const float*)d_in[2];   // (2304,768)
    const float* projw = (const float*)d_in[3];   // (768,768)
    const float* projb = (const float*)d_in[4];   // (768,)
    float* out = (float*)d_out;

    char* ws = (char*)d_ws;
    ushort* xbf   = (ushort*)(ws);                 // 6,291,456 elems
    ushort* wbf   = (ushort*)(ws + 12582912);      // 1,769,472
    ushort* pwbf  = (ushort*)(ws + 16121856);      //   589,824
    ushort* qb    = (ushort*)(ws + 17301504);      // 6,291,456
    ushort* kb    = (ushort*)(ws + 29884416);
    ushort* vb    = (ushort*)(ws + 42467328);
    ushort* attnb = (ushort*)(ws + 55050240);      // ends at 67,633,152 B

    cvt_f32_bf16<<<6144, 256, 0, stream>>>(x, xbf, 6291456);
    cvt_f32_bf16<<<1728, 256, 0, stream>>>(qkvw, wbf, 1769472);
    cvt_f32_bf16<<<576, 256, 0, stream>>>(projw, pwbf, 589824);

    gemm_nt<0><<<dim3(64, 18), 256, 0, stream>>>(xbf, wbf, qb, kb, vb, nullptr, nullptr);
    attn_kernel<<<768, 256, 0, stream>>>(qb, kb, vb, rel, attnb);
    gemm_nt<1><<<dim3(64, 6), 256, 0, stream>>>(attnb, pwbf, nullptr, nullptr, nullptr, projb, out);
}

// Round 4
// 172.126 us; speedup vs baseline: 1.1735x; 1.0292x over previous
//
#include <hip/hip_runtime.h>
#include <hip/hip_bf16.h>
#include <stdint.h>

#define HEADS 12
#define HD 64
#define SEQ 1024
#define CDIM 768

typedef __attribute__((ext_vector_type(8))) short bfrag;   // 8 bf16 (4 VGPRs)
typedef __attribute__((ext_vector_type(4))) float facc;    // 4 fp32 accum

__device__ __forceinline__ ushort f2bf(float f) {
    union { float f; uint32_t u; } v; v.f = f;
    uint32_t u = v.u;
    uint32_t r = (u + 0x7FFFu + ((u >> 16) & 1u)) >> 16;
    return (ushort)r;
}
__device__ __forceinline__ float h2f(uint32_t u16) {
    union { _Float16 h; ushort u; } c; c.u = (ushort)u16; return (float)c.h;
}

// ---------------- fp32 -> bf16 convert ----------------
__global__ void cvt_f32_bf16(const float* __restrict__ s, ushort* __restrict__ d, int n) {
    int i = (blockIdx.x * 256 + threadIdx.x) * 4;
    if (i + 3 < n) {
        float4 v = *(const float4*)(s + i);
        ushort4 o;
        o.x = f2bf(v.x); o.y = f2bf(v.y); o.z = f2bf(v.z); o.w = f2bf(v.w);
        *(ushort4*)(d + i) = o;
    }
}

// ---------------- fp32 -> fp16 convert (bias) ----------------
__global__ void cvt_f32_f16(const float* __restrict__ s, ushort* __restrict__ d, int n) {
    int i = (blockIdx.x * 256 + threadIdx.x) * 4;
    if (i + 3 < n) {
        float4 v = *(const float4*)(s + i);
        union { _Float16 h; ushort u; } c0, c1, c2, c3;
        c0.h = (_Float16)v.x; c1.h = (_Float16)v.y;
        c2.h = (_Float16)v.z; c3.h = (_Float16)v.w;
        ushort4 o = {c0.u, c1.u, c2.u, c3.u};
        *(ushort4*)(d + i) = o;
    }
}

#define GLOAD16(gsrc, ldst) \
    __builtin_amdgcn_global_load_lds((const __attribute__((address_space(1))) uint32_t*)(gsrc), \
                                     (__attribute__((address_space(3))) uint32_t*)(ldst), 16, 0, 0)

// ---------------- NT GEMM, 128x128 tile, BK=32, global_load_lds staging ----------------
template<int EPI>
__global__ __launch_bounds__(256) void gemm_nt(
    const ushort* __restrict__ A, const ushort* __restrict__ Bm,
    ushort* __restrict__ qb, ushort* __restrict__ kb, ushort* __restrict__ vb,
    const float* __restrict__ projb, float* __restrict__ out)
{
    __shared__ ushort As[128 * 32];
    __shared__ ushort Bs[128 * 32];
    const int t = threadIdx.x;
    const int w = t >> 6, l = t & 63;
    const int wm = w >> 1, wn = w & 1;
    const int lr = l & 15, lg = l >> 4;
    const int m0 = blockIdx.x * 128;
    const int o0 = blockIdx.y * 128;

    facc acc[4][4] = {};

    const int srow = w * 16 + (l >> 2);
    const int scol = (l & 3) * 8;
    const ushort* Ag = A + (size_t)(m0 + srow) * CDIM + scol;
    const ushort* Bg = Bm + (size_t)(o0 + srow) * CDIM + scol;

    for (int k0 = 0; k0 < CDIM; k0 += 32) {
        __syncthreads();
        GLOAD16(Ag + k0,             As + w * 512);
        GLOAD16(Ag + 64 * CDIM + k0, As + 2048 + w * 512);
        GLOAD16(Bg + k0,             Bs + w * 512);
        GLOAD16(Bg + 64 * CDIM + k0, Bs + 2048 + w * 512);
        __syncthreads();
        bfrag af[4], bf[4];
#pragma unroll
        for (int m = 0; m < 4; ++m)
            af[m] = *(const bfrag*)&As[(wm * 64 + m * 16 + lr) * 32 + lg * 8];
#pragma unroll
        for (int n = 0; n < 4; ++n)
            bf[n] = *(const bfrag*)&Bs[(wn * 64 + n * 16 + lr) * 32 + lg * 8];
#pragma unroll
        for (int m = 0; m < 4; ++m)
#pragma unroll
            for (int n = 0; n < 4; ++n)
                acc[m][n] = __builtin_amdgcn_mfma_f32_16x16x32_bf16(af[m], bf[n], acc[m][n], 0, 0, 0);
    }

    if (EPI == 0) {
        const int tsel = o0 / CDIM;
        const int h_base = (o0 % CDIM) / 64;
        ushort* dst = (tsel == 0) ? qb : ((tsel == 1) ? kb : vb);
        const float scl = (tsel == 0) ? 0.125f : 1.0f;
#pragma unroll
        for (int m = 0; m < 4; ++m) {
            int grow = m0 + wm * 64 + m * 16 + lg * 4;
#pragma unroll
            for (int n = 0; n < 4; ++n) {
                int h = h_base + wn;
                int d = n * 16 + lr;
#pragma unroll
                for (int r = 0; r < 4; ++r) {
                    int row = grow + r;
                    int b = row >> 10, nn = row & 1023;
                    dst[(((size_t)(b * HEADS + h)) * SEQ + nn) * HD + d] = f2bf(acc[m][n][r] * scl);
                }
            }
        }
    } else {
#pragma unroll
        for (int m = 0; m < 4; ++m) {
            int grow = m0 + wm * 64 + m * 16 + lg * 4;
#pragma unroll
            for (int n = 0; n < 4; ++n) {
                int o = o0 + wn * 64 + n * 16 + lr;
                float bias = projb[o];
#pragma unroll
                for (int r = 0; r < 4; ++r)
                    out[(size_t)(grow + r) * CDIM + o] = acc[m][n][r] + bias;
            }
        }
    }
}

// ---------------- fused flash attention, swapped-QK^T, software-pipelined ----------------
// grid: 768 blocks (XCD-swizzled). Block = 128 q rows; 4 waves x 32 q rows.
__global__ __launch_bounds__(256, 3) void attn_kernel(
    const ushort* __restrict__ qbuf, const ushort* __restrict__ kbuf,
    const ushort* __restrict__ vbuf, const ushort* __restrict__ biash,
    ushort* __restrict__ attn_out)
{
    __shared__ ushort Ks[64 * 72];       // K chunk [kv][hd], padded
    __shared__ ushort Vt[64 * 72];       // V chunk transposed [hd][kv], padded
    __shared__ ushort Ps[4][32 * 72];    // per-wave P [q=32][kv=64], padded

    const int t = threadIdx.x;
    const int w = t >> 6, l = t & 63;
    const int lr = l & 15, lg = l >> 4;

    // XCD-chunked swizzle: lid = h*64 + qt*8 + b; XCD x gets 96 consecutive lids
    const int bid = blockIdx.x;
    const int lid = (bid & 7) * 96 + (bid >> 3);
    const int h  = lid >> 6;
    const int qt = (lid >> 3) & 7;
    const int b  = lid & 7;

    const int q0 = qt * 128;
    const size_t headoff = (size_t)(b * HEADS + h) * SEQ * HD;
    const int qrb = q0 + w * 32;

    // Q fragments (q pre-scaled by 0.125): aQ[n][ks]
    bfrag aQ[2][2];
#pragma unroll
    for (int n = 0; n < 2; ++n) {
        const ushort* Qp = qbuf + headoff + (size_t)(qrb + n * 16 + lr) * HD;
        aQ[n][0] = *(const bfrag*)(Qp + lg * 8);
        aQ[n][1] = *(const bfrag*)(Qp + 32 + lg * 8);
    }

    float mrun[2] = {-1e30f, -1e30f}, lrun[2] = {0.0f, 0.0f};
    facc Ov[2][4] = {};

    const ushort* bprow[2];
#pragma unroll
    for (int n = 0; n < 2; ++n)
        bprow[n] = biash + ((size_t)h * SEQ + qrb + n * 16 + lr) * SEQ;

    // staging thread roles
    const int krow = t >> 3, kc = (t & 7) * 8;   // K: rows krow, krow+32
    const int p2 = t & 31, vg_ = t >> 5;         // V: kv pair 2*p2, d-group vg_
    const ushort* kgb = kbuf + headoff + (size_t)krow * HD + kc;
    const ushort* vgb = vbuf + headoff + (size_t)(2 * p2) * HD + vg_ * 8;

    // ---- prologue: load + stage tile 0 ----
    bfrag krA = *(const bfrag*)(kgb);
    bfrag krB = *(const bfrag*)(kgb + (size_t)32 * HD);
    bfrag vrA = *(const bfrag*)(vgb);
    bfrag vrB = *(const bfrag*)(vgb + HD);
    uint2 bcur[2][4];
#pragma unroll
    for (int n = 0; n < 2; ++n)
#pragma unroll
        for (int c = 0; c < 4; ++c)
            bcur[n][c] = *(const uint2*)(bprow[n] + c * 16 + lg * 4);

    *(bfrag*)&Ks[krow * 72 + kc] = krA;
    *(bfrag*)&Ks[(krow + 32) * 72 + kc] = krB;
#pragma unroll
    for (int i = 0; i < 8; ++i) {
        uint32_t pk = (uint32_t)(uint16_t)vrA[i] | ((uint32_t)(uint16_t)vrB[i] << 16);
        *(uint32_t*)&Vt[(vg_ * 8 + i) * 72 + 2 * p2] = pk;
    }
    __syncthreads();

    for (int tt = 0; tt < 16; ++tt) {
        const int kv0 = tt << 6;
        uint2 bnxt[2][4];
        if (tt < 15) {
            // T14: issue next-tile global loads (K,V,bias) — land during this tile's compute
            const int kvn = kv0 + 64;
            krA = *(const bfrag*)(kgb + (size_t)kvn * HD);
            krB = *(const bfrag*)(kgb + (size_t)(kvn + 32) * HD);
            vrA = *(const bfrag*)(vgb + (size_t)kvn * HD);
            vrB = *(const bfrag*)(vgb + (size_t)(kvn + 1) * HD);
#pragma unroll
            for (int n = 0; n < 2; ++n)
#pragma unroll
                for (int c = 0; c < 4; ++c)
                    bnxt[n][c] = *(const uint2*)(bprow[n] + kvn + c * 16 + lg * 4);
        }

        // S^T = K Q^T : kv = c*16 + lg*4 + r, q = lr
        facc St[2][4];
        __builtin_amdgcn_s_setprio(1);
#pragma unroll
        for (int c = 0; c < 4; ++c) {
            bfrag kf0 = *(const bfrag*)&Ks[(c * 16 + lr) * 72 + lg * 8];
            bfrag kf1 = *(const bfrag*)&Ks[(c * 16 + lr) * 72 + 32 + lg * 8];
#pragma unroll
            for (int n = 0; n < 2; ++n) {
                facc s = {};
                s = __builtin_amdgcn_mfma_f32_16x16x32_bf16(kf0, aQ[n][0], s, 0, 0, 0);
                s = __builtin_amdgcn_mfma_f32_16x16x32_bf16(kf1, aQ[n][1], s, 0, 0, 0);
                St[n][c] = s;
            }
        }
        __builtin_amdgcn_s_setprio(0);

        // bias add (prefetched fp16 regs)
#pragma unroll
        for (int n = 0; n < 2; ++n)
#pragma unroll
            for (int c = 0; c < 4; ++c) {
                uint2 bb = bcur[n][c];
                St[n][c][0] += h2f(bb.x & 0xffffu);
                St[n][c][1] += h2f(bb.x >> 16);
                St[n][c][2] += h2f(bb.y & 0xffffu);
                St[n][c][3] += h2f(bb.y >> 16);
            }

        // row max (lane owns q=lr); reduce across lg with 2 shuffles
        float pmax[2];
#pragma unroll
        for (int n = 0; n < 2; ++n) {
            float m0 = fmaxf(fmaxf(St[n][0][0], St[n][0][1]), fmaxf(St[n][0][2], St[n][0][3]));
            float m1 = fmaxf(fmaxf(St[n][1][0], St[n][1][1]), fmaxf(St[n][1][2], St[n][1][3]));
            float m2 = fmaxf(fmaxf(St[n][2][0], St[n][2][1]), fmaxf(St[n][2][2], St[n][2][3]));
            float m3 = fmaxf(fmaxf(St[n][3][0], St[n][3][1]), fmaxf(St[n][3][2], St[n][3][3]));
            float mx = fmaxf(fmaxf(m0, m1), fmaxf(m2, m3));
            mx = fmaxf(mx, __shfl_xor(mx, 16));
            mx = fmaxf(mx, __shfl_xor(mx, 32));
            pmax[n] = mx;
        }

        // T13 defer-max: rescale only if some row's max grew past mrun+8
        int ok = (pmax[0] <= mrun[0] + 8.0f) && (pmax[1] <= mrun[1] + 8.0f);
        if (!__all(ok)) {
            float al[2];
#pragma unroll
            for (int n = 0; n < 2; ++n) {
                float mnew = fmaxf(mrun[n], pmax[n]);
                al[n] = __expf(mrun[n] - mnew);
                mrun[n] = mnew;
                lrun[n] *= al[n];
            }
#pragma unroll
            for (int n = 0; n < 2; ++n)
#pragma unroll
                for (int r = 0; r < 4; ++r) {
                    float a = __shfl(al[n], lg * 4 + r);
#pragma unroll
                    for (int d = 0; d < 4; ++d) Ov[n][d][r] *= a;
                }
        }

        // exp, row-sum, pack P -> LDS
#pragma unroll
        for (int n = 0; n < 2; ++n) {
            float sum = 0.0f;
#pragma unroll
            for (int c = 0; c < 4; ++c) {
#pragma unroll
                for (int r = 0; r < 4; ++r) {
                    float p = __expf(St[n][c][r] - mrun[n]);
                    St[n][c][r] = p;
                    sum += p;
                }
                ushort4 pk = {f2bf(St[n][c][0]), f2bf(St[n][c][1]),
                              f2bf(St[n][c][2]), f2bf(St[n][c][3])};
                *(ushort4*)&Ps[w][(n * 16 + lr) * 72 + c * 16 + lg * 4] = pk;
            }
            sum += __shfl_xor(sum, 16);
            sum += __shfl_xor(sum, 32);
            lrun[n] += sum;
        }

        // PV
        bfrag aP[2][2];
#pragma unroll
        for (int n = 0; n < 2; ++n) {
            aP[n][0] = *(const bfrag*)&Ps[w][(n * 16 + lr) * 72 + lg * 8];
            aP[n][1] = *(const bfrag*)&Ps[w][(n * 16 + lr) * 72 + 32 + lg * 8];
        }
        __builtin_amdgcn_s_setprio(1);
#pragma unroll
        for (int d = 0; d < 4; ++d) {
            bfrag bv0 = *(const bfrag*)&Vt[(d * 16 + lr) * 72 + lg * 8];
            bfrag bv1 = *(const bfrag*)&Vt[(d * 16 + lr) * 72 + 32 + lg * 8];
#pragma unroll
            for (int n = 0; n < 2; ++n) {
                Ov[n][d] = __builtin_amdgcn_mfma_f32_16x16x32_bf16(aP[n][0], bv0, Ov[n][d], 0, 0, 0);
                Ov[n][d] = __builtin_amdgcn_mfma_f32_16x16x32_bf16(aP[n][1], bv1, Ov[n][d], 0, 0, 0);
            }
        }
        __builtin_amdgcn_s_setprio(0);

        if (tt < 15) {
            __syncthreads();   // all waves done reading Ks/Vt
            *(bfrag*)&Ks[krow * 72 + kc] = krA;
            *(bfrag*)&Ks[(krow + 32) * 72 + kc] = krB;
#pragma unroll
            for (int i = 0; i < 8; ++i) {
                uint32_t pk = (uint32_t)(uint16_t)vrA[i] | ((uint32_t)(uint16_t)vrB[i] << 16);
                *(uint32_t*)&Vt[(vg_ * 8 + i) * 72 + 2 * p2] = pk;
            }
#pragma unroll
            for (int n = 0; n < 2; ++n)
#pragma unroll
                for (int c = 0; c < 4; ++c)
                    bcur[n][c] = bnxt[n][c];
            __syncthreads();   // next tile staged
        }
    }

    // epilogue: normalize, write [b][n][h*64+d] bf16
#pragma unroll
    for (int n = 0; n < 2; ++n) {
        ushort* op = attn_out + ((size_t)b * SEQ + qrb + n * 16) * CDIM + h * HD;
#pragma unroll
        for (int r = 0; r < 4; ++r) {
            float ll = __shfl(lrun[n], lg * 4 + r);
            float rl = 1.0f / ll;
#pragma unroll
            for (int d = 0; d < 4; ++d)
                op[(size_t)(lg * 4 + r) * CDIM + d * 16 + lr] = f2bf(Ov[n][d][r] * rl);
        }
    }
}

// ---------------- launch ----------------
extern "C" void kernel_launch(void* const* d_in, const int* in_sizes, int n_in,
                              void* d_out, int out_size, void* d_ws, size_t ws_size,
                              hipStream_t stream) {
    const float* x     = (const float*)d_in[0];   // (8,1024,768)
    const float* rel   = (const float*)d_in[1];   // (12,1024,1024)
    const float* qkvw  = (const float*)d_in[2];   // (2304,768)
    const float* projw = (const float*)d_in[3];   // (768,768)
    const float* projb = (const float*)d_in[4];   // (768,)
    float* out = (float*)d_out;

    // Workspace layout (80,216,064 B total). attnb aliases xbf: xbf is dead
    // (consumed by gemm<0>) before attn writes attnb; attn fully overwrites it.
    char* ws = (char*)d_ws;
    ushort* biash = (ushort*)(ws);                 // 12,582,912 halves = 25,165,824 B
    ushort* qb    = (ushort*)(ws + 25165824);      // 12,582,912 B
    ushort* kb    = (ushort*)(ws + 37748736);
    ushort* vb    = (ushort*)(ws + 50331648);
    ushort* attnb = (ushort*)(ws + 62914560);      // shared with xbf
    ushort* xbf   = attnb;
    ushort* wbf   = (ushort*)(ws + 75497472);      // 3,538,944 B
    ushort* pwbf  = (ushort*)(ws + 79036416);      // 1,179,648 B -> end 80,216,064

    cvt_f32_bf16<<<6144, 256, 0, stream>>>(x, xbf, 6291456);
    cvt_f32_bf16<<<1728, 256, 0, stream>>>(qkvw, wbf, 1769472);
    cvt_f32_bf16<<<576, 256, 0, stream>>>(projw, pwbf, 589824);
    cvt_f32_f16<<<12288, 256, 0, stream>>>(rel, biash, 12582912);

    gemm_nt<0><<<dim3(64, 18), 256, 0, stream>>>(xbf, wbf, qb, kb, vb, nullptr, nullptr);
    attn_kernel<<<768, 256, 0, stream>>>(qb, kb, vb, biash, attnb);
    gemm_nt<1><<<dim3(64, 6), 256, 0, stream>>>(attnb, pwbf, nullptr, nullptr, nullptr, projb, out);
}

// Round 5
// 155.195 us; speedup vs baseline: 1.3016x; 1.1091x over previous
//
#include <hip/hip_runtime.h>
#include <hip/hip_bf16.h>
#include <stdint.h>

#define HEADS 12
#define HD 64
#define SEQ 1024
#define CDIM 768

typedef __attribute__((ext_vector_type(8))) short bfrag;     // 8 bf16 (4 VGPRs)
typedef __attribute__((ext_vector_type(4))) float facc;      // 4 fp32 accum
typedef __attribute__((ext_vector_type(4))) _Float16 h4;     // 4 fp16 (2 VGPRs)

__device__ __forceinline__ ushort f2bf(float f) {
    union { float f; uint32_t u; } v; v.f = f;
    uint32_t u = v.u;
    uint32_t r = (u + 0x7FFFu + ((u >> 16) & 1u)) >> 16;
    return (ushort)r;
}
__device__ __forceinline__ ushort f2h(float f) {
    union { _Float16 h; ushort u; } c; c.h = (_Float16)f; return c.u;
}
__device__ __forceinline__ float h2f(uint32_t u16) {
    union { _Float16 h; ushort u; } c; c.u = (ushort)u16; return (float)c.h;
}

// ---------------- fused fp32 -> bf16/fp16 converts (one launch) ----------------
// segments: x (bf16), qkvw (bf16), projw (bf16), rel (fp16 * log2e)
__global__ void cvt_all(const float* __restrict__ x, const float* __restrict__ qw,
                        const float* __restrict__ pw, const float* __restrict__ rel,
                        ushort* __restrict__ xd, ushort* __restrict__ qd,
                        ushort* __restrict__ pd, ushort* __restrict__ rd) {
    long i = ((long)blockIdx.x * 256 + threadIdx.x) * 4;
    if (i < 6291456) {
        float4 v = *(const float4*)(x + i);
        ushort4 o = {f2bf(v.x), f2bf(v.y), f2bf(v.z), f2bf(v.w)};
        *(ushort4*)(xd + i) = o;
    } else if (i < 8060928) {
        long j = i - 6291456;
        float4 v = *(const float4*)(qw + j);
        ushort4 o = {f2bf(v.x), f2bf(v.y), f2bf(v.z), f2bf(v.w)};
        *(ushort4*)(qd + j) = o;
    } else if (i < 8650752) {
        long j = i - 8060928;
        float4 v = *(const float4*)(pw + j);
        ushort4 o = {f2bf(v.x), f2bf(v.y), f2bf(v.z), f2bf(v.w)};
        *(ushort4*)(pd + j) = o;
    } else {
        long j = i - 8650752;
        float4 v = *(const float4*)(rel + j);
        ushort4 o = {f2h(v.x * 1.44269504f), f2h(v.y * 1.44269504f),
                     f2h(v.z * 1.44269504f), f2h(v.w * 1.44269504f)};
        *(ushort4*)(rd + j) = o;
    }
}

#define GLOAD16(gsrc, ldst) \
    __builtin_amdgcn_global_load_lds((const __attribute__((address_space(1))) uint32_t*)(gsrc), \
                                     (__attribute__((address_space(3))) uint32_t*)(ldst), 16, 0, 0)

// ---------------- NT GEMM, 128x128 tile, BK=32, global_load_lds staging ----------------
// EPI 0: scatter q (bf16, *0.125*log2e), k (bf16), v (fp16)
// EPI 1: out fp32 += proj bias
template<int EPI>
__global__ __launch_bounds__(256) void gemm_nt(
    const ushort* __restrict__ A, const ushort* __restrict__ Bm,
    ushort* __restrict__ qb, ushort* __restrict__ kb, ushort* __restrict__ vb,
    const float* __restrict__ projb, float* __restrict__ out)
{
    __shared__ ushort As[128 * 32];
    __shared__ ushort Bs[128 * 32];
    const int t = threadIdx.x;
    const int w = t >> 6, l = t & 63;
    const int wm = w >> 1, wn = w & 1;
    const int lr = l & 15, lg = l >> 4;
    const int m0 = blockIdx.x * 128;
    const int o0 = blockIdx.y * 128;

    facc acc[4][4] = {};

    const int srow = w * 16 + (l >> 2);
    const int scol = (l & 3) * 8;
    const ushort* Ag = A + (size_t)(m0 + srow) * CDIM + scol;
    const ushort* Bg = Bm + (size_t)(o0 + srow) * CDIM + scol;

    for (int k0 = 0; k0 < CDIM; k0 += 32) {
        __syncthreads();
        GLOAD16(Ag + k0,             As + w * 512);
        GLOAD16(Ag + 64 * CDIM + k0, As + 2048 + w * 512);
        GLOAD16(Bg + k0,             Bs + w * 512);
        GLOAD16(Bg + 64 * CDIM + k0, Bs + 2048 + w * 512);
        __syncthreads();
        bfrag af[4], bf[4];
#pragma unroll
        for (int m = 0; m < 4; ++m)
            af[m] = *(const bfrag*)&As[(wm * 64 + m * 16 + lr) * 32 + lg * 8];
#pragma unroll
        for (int n = 0; n < 4; ++n)
            bf[n] = *(const bfrag*)&Bs[(wn * 64 + n * 16 + lr) * 32 + lg * 8];
#pragma unroll
        for (int m = 0; m < 4; ++m)
#pragma unroll
            for (int n = 0; n < 4; ++n)
                acc[m][n] = __builtin_amdgcn_mfma_f32_16x16x32_bf16(af[m], bf[n], acc[m][n], 0, 0, 0);
    }

    if (EPI == 0) {
        const int tsel = o0 / CDIM;
        const int h_base = (o0 % CDIM) / 64;
        ushort* dst = (tsel == 0) ? qb : ((tsel == 1) ? kb : vb);
        const float scl = (tsel == 0) ? 0.18033688f : 1.0f;   // 0.125 * log2(e) for q
#pragma unroll
        for (int m = 0; m < 4; ++m) {
            int grow = m0 + wm * 64 + m * 16 + lg * 4;
#pragma unroll
            for (int n = 0; n < 4; ++n) {
                int h = h_base + wn;
                int d = n * 16 + lr;
#pragma unroll
                for (int r = 0; r < 4; ++r) {
                    int row = grow + r;
                    int b = row >> 10, nn = row & 1023;
                    ushort val = (tsel == 2) ? f2h(acc[m][n][r])
                                             : f2bf(acc[m][n][r] * scl);
                    dst[(((size_t)(b * HEADS + h)) * SEQ + nn) * HD + d] = val;
                }
            }
        }
    } else {
#pragma unroll
        for (int m = 0; m < 4; ++m) {
            int grow = m0 + wm * 64 + m * 16 + lg * 4;
#pragma unroll
            for (int n = 0; n < 4; ++n) {
                int o = o0 + wn * 64 + n * 16 + lr;
                float bias = projb[o];
#pragma unroll
                for (int r = 0; r < 4; ++r)
                    out[(size_t)(grow + r) * CDIM + o] = acc[m][n][r] + bias;
            }
        }
    }
}

// ---------------- fused flash attention: swapped-QK^T, in-register P, dbuf K/V ----------------
// grid: 768 (XCD-swizzled). Block = 128 q rows; 4 waves x 32 q rows (2 subtiles).
// Softmax in exp2 domain (q and bias pre-scaled by log2e).
__global__ __launch_bounds__(256, 3) void attn_kernel(
    const ushort* __restrict__ qbuf, const ushort* __restrict__ kbuf,
    const ushort* __restrict__ vbuf, const ushort* __restrict__ biash,
    ushort* __restrict__ attn_out)
{
    __shared__ ushort Ks[2][64 * 72];    // K chunk [kv][hd] bf16, padded, double-buffered
    __shared__ ushort Vt[2][64 * 72];    // V chunk transposed [hd][kv] fp16, padded, dbuf

    const int t = threadIdx.x;
    const int w = t >> 6, l = t & 63;
    const int lr = l & 15, lg = l >> 4;

    const int bid = blockIdx.x;
    const int lid = (bid & 7) * 96 + (bid >> 3);   // XCD-chunked swizzle
    const int h  = lid >> 6;
    const int qt = (lid >> 3) & 7;
    const int b  = lid & 7;

    const int q0 = qt * 128;
    const size_t headoff = (size_t)(b * HEADS + h) * SEQ * HD;
    const int qrb = q0 + w * 32;

    // Q fragments (pre-scaled by 0.125*log2e)
    bfrag aQ[2][2];
#pragma unroll
    for (int n = 0; n < 2; ++n) {
        const ushort* Qp = qbuf + headoff + (size_t)(qrb + n * 16 + lr) * HD;
        aQ[n][0] = *(const bfrag*)(Qp + lg * 8);
        aQ[n][1] = *(const bfrag*)(Qp + 32 + lg * 8);
    }

    float mrun[2] = {-1e30f, -1e30f}, lrun[2] = {0.0f, 0.0f};
    facc Ov[2][4] = {};

    const ushort* bprow[2];
#pragma unroll
    for (int n = 0; n < 2; ++n)
        bprow[n] = biash + ((size_t)h * SEQ + qrb + n * 16 + lr) * SEQ;

    // staging roles
    const int krow = t >> 3, kc = (t & 7) * 8;   // K rows krow, krow+32
    const int p2 = t & 31, vg_ = t >> 5;         // V kv-pair 2*p2, d-group vg_
    const ushort* kgb = kbuf + headoff + (size_t)krow * HD + kc;
    const ushort* vgb = vbuf + headoff + (size_t)(2 * p2) * HD + vg_ * 8;

    // ---- prologue: tile0 load+stage, tile1 load, bias0 load ----
    bfrag krA = *(const bfrag*)(kgb);
    bfrag krB = *(const bfrag*)(kgb + (size_t)32 * HD);
    bfrag vrA = *(const bfrag*)(vgb);
    bfrag vrB = *(const bfrag*)(vgb + HD);
    uint2 bcur[2][4], bnxt[2][4];
#pragma unroll
    for (int n = 0; n < 2; ++n)
#pragma unroll
        for (int c = 0; c < 4; ++c)
            bcur[n][c] = *(const uint2*)(bprow[n] + c * 16 + lg * 4);

    *(bfrag*)&Ks[0][krow * 72 + kc] = krA;
    *(bfrag*)&Ks[0][(krow + 32) * 72 + kc] = krB;
#pragma unroll
    for (int i = 0; i < 8; ++i) {
        uint32_t pk = (uint32_t)(uint16_t)vrA[i] | ((uint32_t)(uint16_t)vrB[i] << 16);
        *(uint32_t*)&Vt[0][(vg_ * 8 + i) * 72 + 2 * p2] = pk;
    }
    // tile1 global loads (land during tile0 compute)
    krA = *(const bfrag*)(kgb + (size_t)64 * HD);
    krB = *(const bfrag*)(kgb + (size_t)96 * HD);
    vrA = *(const bfrag*)(vgb + (size_t)64 * HD);
    vrB = *(const bfrag*)(vgb + (size_t)65 * HD);
    __syncthreads();

    for (int tt = 0; tt < 16; ++tt) {
        const int cur = tt & 1;
        const ushort* Kc = Ks[cur];
        const ushort* Vc = Vt[cur];

        // (1) S^T = K Q^T with C-init = bias (exp2 domain)
        facc St[2][4];
        __builtin_amdgcn_s_setprio(1);
#pragma unroll
        for (int c = 0; c < 4; ++c) {
            bfrag kf0 = *(const bfrag*)&Kc[(c * 16 + lr) * 72 + lg * 8];
            bfrag kf1 = *(const bfrag*)&Kc[(c * 16 + lr) * 72 + 32 + lg * 8];
#pragma unroll
            for (int n = 0; n < 2; ++n) {
                uint2 bb = bcur[n][c];
                facc s;
                s[0] = h2f(bb.x & 0xffffu);
                s[1] = h2f(bb.x >> 16);
                s[2] = h2f(bb.y & 0xffffu);
                s[3] = h2f(bb.y >> 16);
                s = __builtin_amdgcn_mfma_f32_16x16x32_bf16(kf0, aQ[n][0], s, 0, 0, 0);
                s = __builtin_amdgcn_mfma_f32_16x16x32_bf16(kf1, aQ[n][1], s, 0, 0, 0);
                St[n][c] = s;
            }
        }
        __builtin_amdgcn_s_setprio(0);

        // (1.5) bias prefetch for tile tt+1
        if (tt < 15) {
            const int kvn = (tt + 1) << 6;
#pragma unroll
            for (int n = 0; n < 2; ++n)
#pragma unroll
                for (int c = 0; c < 4; ++c)
                    bnxt[n][c] = *(const uint2*)(bprow[n] + kvn + c * 16 + lg * 4);
        }

        // row max (lane owns q=lr), reduce across lg
        float pmax[2];
#pragma unroll
        for (int n = 0; n < 2; ++n) {
            float m0 = fmaxf(fmaxf(St[n][0][0], St[n][0][1]), fmaxf(St[n][0][2], St[n][0][3]));
            float m1 = fmaxf(fmaxf(St[n][1][0], St[n][1][1]), fmaxf(St[n][1][2], St[n][1][3]));
            float m2 = fmaxf(fmaxf(St[n][2][0], St[n][2][1]), fmaxf(St[n][2][2], St[n][2][3]));
            float m3 = fmaxf(fmaxf(St[n][3][0], St[n][3][1]), fmaxf(St[n][3][2], St[n][3][3]));
            float mx = fmaxf(fmaxf(m0, m1), fmaxf(m2, m3));
            mx = fmaxf(mx, __shfl_xor(mx, 16));
            mx = fmaxf(mx, __shfl_xor(mx, 32));
            pmax[n] = mx;
        }

        // T13 defer-max (threshold 8 nats = 11.5416 in exp2 domain)
        int ok = (pmax[0] <= mrun[0] + 11.541560f) && (pmax[1] <= mrun[1] + 11.541560f);
        if (!__all(ok)) {
            float al[2];
#pragma unroll
            for (int n = 0; n < 2; ++n) {
                float mnew = fmaxf(mrun[n], pmax[n]);
                al[n] = exp2f(mrun[n] - mnew);
                mrun[n] = mnew;
                lrun[n] *= al[n];
            }
#pragma unroll
            for (int n = 0; n < 2; ++n)
#pragma unroll
                for (int r = 0; r < 4; ++r) {
                    float a = __shfl(al[n], lg * 4 + r);
#pragma unroll
                    for (int d = 0; d < 4; ++d) Ov[n][d][r] *= a;
                }
        }

        // exp2, row-sum, P -> fp16 regs (A-fragments for mfma 16x16x16)
        h4 pf[2][4];
#pragma unroll
        for (int n = 0; n < 2; ++n) {
            float sum = 0.0f;
#pragma unroll
            for (int c = 0; c < 4; ++c) {
#pragma unroll
                for (int r = 0; r < 4; ++r) {
                    float p = exp2f(St[n][c][r] - mrun[n]);
                    sum += p;
                    pf[n][c][r] = (_Float16)p;
                }
            }
            sum += __shfl_xor(sum, 16);
            sum += __shfl_xor(sum, 32);
            lrun[n] += sum;
        }

        // (2) stage tile tt+1 regs -> LDS (other buffer)
        if (tt < 15) {
            *(bfrag*)&Ks[cur ^ 1][krow * 72 + kc] = krA;
            *(bfrag*)&Ks[cur ^ 1][(krow + 32) * 72 + kc] = krB;
#pragma unroll
            for (int i = 0; i < 8; ++i) {
                uint32_t pk = (uint32_t)(uint16_t)vrA[i] | ((uint32_t)(uint16_t)vrB[i] << 16);
                *(uint32_t*)&Vt[cur ^ 1][(vg_ * 8 + i) * 72 + 2 * p2] = pk;
            }
        }
        // (3) issue global loads for tile tt+2
        if (tt < 14) {
            const int kvn = (tt + 2) << 6;
            krA = *(const bfrag*)(kgb + (size_t)kvn * HD);
            krB = *(const bfrag*)(kgb + (size_t)(kvn + 32) * HD);
            vrA = *(const bfrag*)(vgb + (size_t)kvn * HD);
            vrB = *(const bfrag*)(vgb + (size_t)(kvn + 1) * HD);
        }

        // (4) PV: Ov[q][d] += P[q][kv] * Vt[d][kv], K=16 MFMAs, P in registers
        __builtin_amdgcn_s_setprio(1);
#pragma unroll
        for (int d0 = 0; d0 < 4; ++d0) {
#pragma unroll
            for (int c = 0; c < 4; ++c) {
                h4 bv = *(const h4*)&Vc[(d0 * 16 + lr) * 72 + c * 16 + lg * 4];
#pragma unroll
                for (int n = 0; n < 2; ++n)
                    Ov[n][d0] = __builtin_amdgcn_mfma_f32_16x16x16f16(pf[n][c], bv, Ov[n][d0], 0, 0, 0);
            }
        }
        __builtin_amdgcn_s_setprio(0);

        // (5) single barrier per tile; rotate bias regs
        if (tt < 15) {
            __syncthreads();
#pragma unroll
            for (int n = 0; n < 2; ++n)
#pragma unroll
                for (int c = 0; c < 4; ++c)
                    bcur[n][c] = bnxt[n][c];
        }
    }

    // epilogue: normalize, write [b][n][h*64+d] bf16
#pragma unroll
    for (int n = 0; n < 2; ++n) {
        ushort* op = attn_out + ((size_t)b * SEQ + qrb + n * 16) * CDIM + h * HD;
#pragma unroll
        for (int r = 0; r < 4; ++r) {
            float ll = __shfl(lrun[n], lg * 4 + r);
            float rl = 1.0f / ll;
#pragma unroll
            for (int d = 0; d < 4; ++d)
                op[(size_t)(lg * 4 + r) * CDIM + d * 16 + lr] = f2bf(Ov[n][d][r] * rl);
        }
    }
}

// ---------------- launch ----------------
extern "C" void kernel_launch(void* const* d_in, const int* in_sizes, int n_in,
                              void* d_out, int out_size, void* d_ws, size_t ws_size,
                              hipStream_t stream) {
    const float* x     = (const float*)d_in[0];   // (8,1024,768)
    const float* rel   = (const float*)d_in[1];   // (12,1024,1024)
    const float* qkvw  = (const float*)d_in[2];   // (2304,768)
    const float* projw = (const float*)d_in[3];   // (768,768)
    const float* projb = (const float*)d_in[4];   // (768,)
    float* out = (float*)d_out;

    // Workspace (80,216,064 B). attnb aliases xbf (xbf dead after gemm<0>).
    char* ws = (char*)d_ws;
    ushort* biash = (ushort*)(ws);                 // 12,582,912 halves (fp16, *log2e)
    ushort* qb    = (ushort*)(ws + 25165824);      // bf16
    ushort* kb    = (ushort*)(ws + 37748736);      // bf16
    ushort* vb    = (ushort*)(ws + 50331648);      // fp16
    ushort* attnb = (ushort*)(ws + 62914560);      // bf16 (aliases xbf)
    ushort* xbf   = attnb;
    ushort* wbf   = (ushort*)(ws + 75497472);
    ushort* pwbf  = (ushort*)(ws + 79036416);

    cvt_all<<<20736, 256, 0, stream>>>(x, qkvw, projw, rel, xbf, wbf, pwbf, biash);

    gemm_nt<0><<<dim3(64, 18), 256, 0, stream>>>(xbf, wbf, qb, kb, vb, nullptr, nullptr);
    attn_kernel<<<768, 256, 0, stream>>>(qb, kb, vb, biash, attnb);
    gemm_nt<1><<<dim3(64, 6), 256, 0, stream>>>(attnb, pwbf, nullptr, nullptr, nullptr, projb, out);
}